// Round 12
// baseline (1982.776 us; speedup 1.0000x reference)
//
#include <hip/hip_runtime.h>
#include <cstdint>

// MyRNN: out[b,t,:] = h_t where h_t = tanh(x[b,t,:]@W_xh + b_h + h_{t-1}@W_hh)
// B=64, S=512, D_IN=D_H=1024, fp32 I/O; internal bf16 MFMA.
//
// Round 12 = Round-5 structure (best measured: k_rnn 1444us) with exactly two
// validated deltas:
//  - arrivals are plain flag STORES (64 distinct u32 per bg; no MALL RMW
//    serialization), poll = one dwordx4/lane over the bg's 256B flag block.
//  - padded LDS rows (129 x 16B slots), no XOR (R7-verified layout).
// Everything else identical to R5: OUT stores inside the staging window,
// xp prefetch under the poll, per-wave vmcnt(0) drain before arrival.
// All cross-WG exchange via MALL (sc0 sc1) — XCD-local exchange proven
// unreliable in R9/R10/R11.

#define DIN 1024
#define DH  1024
#define NB  64
#define NS  512
#define SPIN_CAP (1u << 20)

typedef __attribute__((ext_vector_type(8))) unsigned short us8;
typedef __attribute__((ext_vector_type(8))) __bf16 bf8;
typedef __attribute__((ext_vector_type(4))) float f32x4;
typedef __attribute__((ext_vector_type(4))) unsigned int u32x4;

__device__ __forceinline__ unsigned short f32_bf16(float f) {
  unsigned u = __float_as_uint(f);
  u = (u + 0x7fffu + ((u >> 16) & 1u)) >> 16;
  return (unsigned short)u;
}
__device__ __forceinline__ float bf16_f32(unsigned short h) {
  return __uint_as_float(((unsigned)h) << 16);
}
__device__ __forceinline__ bf8 as_bf8(us8 v) { return __builtin_bit_cast(bf8, v); }

// 16B load bypassing to the coherent point (MALL). Caller must s_waitcnt.
__device__ __forceinline__ us8 load_sc16(const us8* p) {
  us8 r;
  asm volatile("global_load_dwordx4 %0, %1, off sc0 sc1"
               : "=v"(r) : "v"(p) : "memory");
  return r;
}
__device__ __forceinline__ u32x4 load_sc16u(const unsigned int* p) {
  u32x4 r;
  asm volatile("global_load_dwordx4 %0, %1, off sc0 sc1"
               : "=v"(r) : "v"(p) : "memory");
  return r;
}

// ---------------------------------------------------------------- transpose
__global__ __launch_bounds__(256) void k_transpose_bf16(
    const float* __restrict__ W, unsigned short* __restrict__ WT) {
  __shared__ float tile[32][33];
  const int b  = blockIdx.x;
  const int bn = (b & 31) * 32;
  const int bk = (b >> 5) * 32;
  const int tx = threadIdx.x & 31, ty = threadIdx.x >> 5;
#pragma unroll
  for (int i = 0; i < 4; ++i)
    tile[ty + i * 8][tx] = W[(size_t)(bk + ty + i * 8) * DH + bn + tx];
  __syncthreads();
#pragma unroll
  for (int i = 0; i < 4; ++i)
    WT[(size_t)(bn + ty + i * 8) * DIN + bk + tx] = f32_bf16(tile[tx][ty + i * 8]);
}

// ---------------------------------------------------------------- phase 1
__device__ __forceinline__ int lds_idx(int row, int slot) {  // ushort units
  return row * 32 + ((slot ^ ((row >> 1) & 3)) << 3);
}

__global__ __launch_bounds__(256) void k_xproj(
    const float* __restrict__ X,             // [B*S][DIN] fp32
    const unsigned short* __restrict__ WT,   // W_xh^T bf16 [n][k]
    unsigned short* __restrict__ XP) {       // bf16 [s][b][h]
  __shared__ unsigned short As[128 * 32];
  __shared__ unsigned short Bs[128 * 32];
  const int tid = threadIdx.x;
  const int m0 = (int)(blockIdx.x >> 3) * 128;
  const int n0 = (int)(blockIdx.x & 7) * 128;
  const int w = tid >> 6, lane = tid & 63;
  const int wm = (w >> 1) * 64, wn = (w & 1) * 64;
  const int l15 = lane & 15, lhi = lane >> 4;
  const int srow = tid >> 1;
  const int s0 = (tid & 1) * 2;
  f32x4 acc[4][4] = {};

  for (int k0 = 0; k0 < DIN; k0 += 32) {
    const float4* ga = reinterpret_cast<const float4*>(
        X + (size_t)(m0 + srow) * DIN + k0 + s0 * 8);
    float4 f0 = ga[0], f1 = ga[1], f2 = ga[2], f3 = ga[3];
    us8 v0, v1;
    v0[0] = f32_bf16(f0.x); v0[1] = f32_bf16(f0.y); v0[2] = f32_bf16(f0.z); v0[3] = f32_bf16(f0.w);
    v0[4] = f32_bf16(f1.x); v0[5] = f32_bf16(f1.y); v0[6] = f32_bf16(f1.z); v0[7] = f32_bf16(f1.w);
    v1[0] = f32_bf16(f2.x); v1[1] = f32_bf16(f2.y); v1[2] = f32_bf16(f2.z); v1[3] = f32_bf16(f2.w);
    v1[4] = f32_bf16(f3.x); v1[5] = f32_bf16(f3.y); v1[6] = f32_bf16(f3.z); v1[7] = f32_bf16(f3.w);
    *(us8*)&As[lds_idx(srow, s0)]     = v0;
    *(us8*)&As[lds_idx(srow, s0 + 1)] = v1;
    const unsigned short* gb = WT + (size_t)(n0 + srow) * DIN + k0 + s0 * 8;
    *(us8*)&Bs[lds_idx(srow, s0)]     = *reinterpret_cast<const us8*>(gb);
    *(us8*)&Bs[lds_idx(srow, s0 + 1)] = *reinterpret_cast<const us8*>(gb + 8);
    __syncthreads();

    bf8 af[4], bfr[4];
#pragma unroll
    for (int i = 0; i < 4; ++i)
      af[i] = as_bf8(*(const us8*)&As[lds_idx(wm + i * 16 + l15, lhi)]);
#pragma unroll
    for (int r = 0; r < 4; ++r)
      bfr[r] = as_bf8(*(const us8*)&Bs[lds_idx(wn + r * 16 + l15, lhi)]);
#pragma unroll
    for (int i = 0; i < 4; ++i)
#pragma unroll
      for (int r = 0; r < 4; ++r)
        acc[i][r] = __builtin_amdgcn_mfma_f32_16x16x32_bf16(af[i], bfr[r], acc[i][r], 0, 0, 0);
    __syncthreads();
  }
#pragma unroll
  for (int i = 0; i < 4; ++i)
#pragma unroll
    for (int r = 0; r < 4; ++r)
#pragma unroll
      for (int j = 0; j < 4; ++j) {
        int gm = m0 + wm + i * 16 + lhi * 4 + j;
        int gn = n0 + wn + r * 16 + l15;
        int orow = ((gm & 511) << 6) | (gm >> 9);
        XP[(size_t)orow * DH + gn] = f32_bf16(acc[i][r][j]);
      }
}

// ---------------------------------------------------------------- phase 2
// 64 WGs x 256 thr. WG g: bg=g>>4 (rows bg*16..+16), ng=g&15; wave w owns
// cols ng*64+w*16..+16. W_hh^T slice resident in 128 VGPRs/wave.
// LDS: 2 x [16 rows][129 16B-slots] (padded; R7-verified layout).
// Arrival: wave w plain-stores flags[bg*64 + ng*4 + w] = t+1 after draining
// its h stores; poll = one dwordx4/lane over the bg's 64 flags + __all.
__global__ __launch_bounds__(256) void k_rnn(
    const unsigned short* __restrict__ WT,  // W_hh^T bf16 [n][k]
    const unsigned short* __restrict__ XP,  // bf16 [s][b][h]
    const float* __restrict__ BH,           // b_h fp32
    float* __restrict__ OUT,                // fp32 [b][s][h]
    unsigned short* __restrict__ H,         // 2 x [NB][DH] bf16
    unsigned int* __restrict__ flags) {     // [4 bg][64] u32 (256B blocks)
  __shared__ us8 hs[2][16 * 129];           // 2 x 33,024B
  const int tid = threadIdx.x, g = blockIdx.x;
  const int w = tid >> 6, lane = tid & 63;
  const int bg = g >> 4, ng = g & 15;
  const int nbase = ng * 64 + w * 16;
  const int rowbase = bg * 16;
  const int l15 = lane & 15, lhi = lane >> 4;
  const int crow = lhi * 4;
  const int th = tid >> 7;                  // staging row parity
  const int c7 = tid & 127;                 // staging chunk-in-row
  const int rbase = l15 * 129;              // read: row base (16B slots)

  // preload W_hh^T fragments: 32 x 16B per lane = 128 VGPRs
  bf8 bw[32];
  const unsigned short* wp = WT + (size_t)(nbase + l15) * DIN + lhi * 8;
#pragma unroll
  for (int kk = 0; kk < 32; ++kk)
    bw[kk] = as_bf8(*reinterpret_cast<const us8*>(wp + kk * 32));

  const float bh = BH[nbase + l15];
  unsigned int* myflag = flags + bg * 64 + ng * 4 + w;
  const unsigned int* fl0 = flags + bg * 64 + l15 * 4;  // lane covers 4 flags

  // prefetch xp for t=0
  float xq[4];
#pragma unroll
  for (int j = 0; j < 4; ++j)
    xq[j] = bf16_f32(XP[(size_t)(rowbase + crow + j) * DH + nbase + l15]);

  float v[4] = {0.f, 0.f, 0.f, 0.f};

#pragma unroll 1
  for (int t = 0; t < NS; ++t) {
    const int pb = t & 1;
    f32x4 a0 = {}, a1 = {}, a2 = {}, a3 = {};
    if (t > 0) {
      // ---- stage h[pb] -> hs[pb]; OUT stores for t-1 ride the window ----
      const us8* hg = reinterpret_cast<const us8*>(H) +
                      (size_t)pb * 8192 + rowbase * 128 + tid;
      us8 hv[8];
#pragma unroll
      for (int i = 0; i < 8; ++i) hv[i] = load_sc16(hg + 256 * i);
#pragma unroll
      for (int j = 0; j < 4; ++j)
        __builtin_nontemporal_store(
            v[j],
            &OUT[((size_t)(rowbase + crow + j) * NS + (t - 1)) * DH + nbase + l15]);
      asm volatile("s_waitcnt vmcnt(0)" ::: "memory");
      __builtin_amdgcn_sched_barrier(0);
#pragma unroll
      for (int i = 0; i < 8; ++i) {
        const int r = 2 * i + th;
        hs[pb][r * 129 + c7] = hv[i];
      }
      __syncthreads();  // the ONLY barrier per step
      // ---- A-fragment reads + 32 MFMA (padded layout) ----
#pragma unroll
      for (int kk = 0; kk < 32; kk += 4) {
        bf8 h0 = as_bf8(hs[pb][rbase + (kk + 0) * 4 + lhi]);
        bf8 h1 = as_bf8(hs[pb][rbase + (kk + 1) * 4 + lhi]);
        bf8 h2 = as_bf8(hs[pb][rbase + (kk + 2) * 4 + lhi]);
        bf8 h3 = as_bf8(hs[pb][rbase + (kk + 3) * 4 + lhi]);
        a0 = __builtin_amdgcn_mfma_f32_16x16x32_bf16(h0, bw[kk],     a0, 0, 0, 0);
        a1 = __builtin_amdgcn_mfma_f32_16x16x32_bf16(h1, bw[kk + 1], a1, 0, 0, 0);
        a2 = __builtin_amdgcn_mfma_f32_16x16x32_bf16(h2, bw[kk + 2], a2, 0, 0, 0);
        a3 = __builtin_amdgcn_mfma_f32_16x16x32_bf16(h3, bw[kk + 3], a3, 0, 0, 0);
      }
    }
    f32x4 s = (a0 + a1) + (a2 + a3);

#pragma unroll
    for (int j = 0; j < 4; ++j) {
      float x = xq[j] + s[j] + bh;
      float e = __expf(-2.f * fabsf(x));
      float r = __fdividef(1.f - e, 1.f + e);
      v[j] = copysignf(r, x);
    }

    if (t < NS - 1) {
      // h stores to coherent point
      unsigned short* hnext = H + (size_t)(pb ^ 1) * (NB * DH);
#pragma unroll
      for (int j = 0; j < 4; ++j)
        __hip_atomic_store(hnext + (size_t)(rowbase + crow + j) * DH + nbase + l15,
                           f32_bf16(v[j]), __ATOMIC_RELAXED, __HIP_MEMORY_SCOPE_AGENT);
      asm volatile("s_waitcnt vmcnt(0)" ::: "memory");  // drain THIS wave's h
      if (lane == 0)  // plain per-wave flag store (distinct address, no RMW)
        __hip_atomic_store(myflag, (unsigned)(t + 1), __ATOMIC_RELAXED,
                           __HIP_MEMORY_SCOPE_AGENT);
      // xp prefetch rides under the poll
#pragma unroll
      for (int j = 0; j < 4; ++j)
        xq[j] = bf16_f32(XP[(size_t)(((t + 1) << 6) + rowbase + crow + j) * DH +
                            nbase + l15]);
      const unsigned tgt = (unsigned)(t + 1);
      for (unsigned it = 0;; ++it) {
        u32x4 fv = load_sc16u(fl0);
        asm volatile("s_waitcnt vmcnt(0)" ::: "memory");
        __builtin_amdgcn_sched_barrier(0);
        int ok = (fv.x >= tgt) & (fv.y >= tgt) & (fv.z >= tgt) & (fv.w >= tgt);
        if (__all(ok)) break;
        if (it > SPIN_CAP) break;  // fail fast, never hang
        __builtin_amdgcn_s_sleep(1);
      }
      asm volatile("" ::: "memory");  // no next-step load hoist above the poll
    }
  }
  // final OUT stores for t = NS-1
#pragma unroll
  for (int j = 0; j < 4; ++j)
    __builtin_nontemporal_store(
        v[j], &OUT[((size_t)(rowbase + crow + j) * NS + (NS - 1)) * DH + nbase + l15]);
}

// ---------------------------------------------------------------- launcher
extern "C" void kernel_launch(void* const* d_in, const int* in_sizes, int n_in,
                              void* d_out, int out_size, void* d_ws, size_t ws_size,
                              hipStream_t stream) {
  (void)in_sizes; (void)n_in; (void)out_size; (void)ws_size;
  const float* X   = (const float*)d_in[0];
  const float* Wxh = (const float*)d_in[1];
  const float* Whh = (const float*)d_in[2];
  const float* bh  = (const float*)d_in[3];
  float* out = (float*)d_out;

  char* ws = (char*)d_ws;
  // layout: wxh_t 2MB | whh_t 2MB | h 256KB | flags 4KB | xp 64MB (@4.5MB)
  unsigned short* wxh_t = (unsigned short*)(ws);
  unsigned short* whh_t = (unsigned short*)(ws + 2097152ull);
  unsigned short* hbuf  = (unsigned short*)(ws + 4194304ull);
  unsigned int*   flg   = (unsigned int*)(ws + 4456448ull);
  unsigned short* xp    = (unsigned short*)(ws + 4718592ull);

  (void)hipMemsetAsync(flg, 0, 4096, stream);  // flags start at 0 each call
  k_transpose_bf16<<<1024, 256, 0, stream>>>(Wxh, wxh_t);
  k_transpose_bf16<<<1024, 256, 0, stream>>>(Whh, whh_t);
  k_xproj<<<2048, 256, 0, stream>>>(X, wxh_t, xp);
  k_rnn<<<64, 256, 0, stream>>>(whh_t, xp, bh, out, hbuf, flg);
}

// Round 13
// 1573.273 us; speedup vs baseline: 1.2603x; 1.2603x over previous
//
#include <hip/hip_runtime.h>
#include <cstdint>

// MyRNN: out[b,t,:] = h_t where h_t = tanh(x[b,t,:]@W_xh + b_h + h_{t-1}@W_hh)
// B=64, S=512, D_IN=D_H=1024, fp32 I/O; internal bf16 MFMA.
//
// Round 13 = EXACT Round-5 kernel (measured best: k_rnn 1444us, total 1601us)
// with ONE delta: OUT stores for t-1 moved from the staging window (where the
// staging vmcnt(0) waited on their HBM acks) to after __syncthreads / before
// the MFMA loop (acks drain under MFMA+tanh, absorbed by the h-store drain).
// Plus a spin cap (hang safety only). Everything else verbatim R5:
//  - arrivals: per-wave atomic fetch_add on 4 lines per bg ((bg*4+w)*64)
//  - poll: 4 wave-uniform scalar atomic loads + s_sleep(1)
//  - LDS: XOR-swizzled [r*128 + (c7 ^ (r&7))] 16B chunks, double-buffered
//  - xp prefetch under the poll; h stores relaxed agent scope (MALL)

#define DIN 1024
#define DH  1024
#define NB  64
#define NS  512
#define SPIN_CAP (1u << 20)

typedef __attribute__((ext_vector_type(8))) unsigned short us8;
typedef __attribute__((ext_vector_type(8))) __bf16 bf8;
typedef __attribute__((ext_vector_type(4))) float f32x4;

__device__ __forceinline__ unsigned short f32_bf16(float f) {
  unsigned u = __float_as_uint(f);
  u = (u + 0x7fffu + ((u >> 16) & 1u)) >> 16;
  return (unsigned short)u;
}
__device__ __forceinline__ float bf16_f32(unsigned short h) {
  return __uint_as_float(((unsigned)h) << 16);
}
__device__ __forceinline__ bf8 as_bf8(us8 v) { return __builtin_bit_cast(bf8, v); }

// 16B load with coherent-point bypass (sc0 sc1). Caller must s_waitcnt.
__device__ __forceinline__ us8 load_sc16(const us8* p) {
  us8 r;
  asm volatile("global_load_dwordx4 %0, %1, off sc0 sc1"
               : "=v"(r) : "v"(p) : "memory");
  return r;
}

// ---------------------------------------------------------------- transpose
__global__ __launch_bounds__(256) void k_transpose_bf16(
    const float* __restrict__ W, unsigned short* __restrict__ WT) {
  __shared__ float tile[32][33];
  const int b  = blockIdx.x;
  const int bn = (b & 31) * 32;
  const int bk = (b >> 5) * 32;
  const int tx = threadIdx.x & 31, ty = threadIdx.x >> 5;
#pragma unroll
  for (int i = 0; i < 4; ++i)
    tile[ty + i * 8][tx] = W[(size_t)(bk + ty + i * 8) * DH + bn + tx];
  __syncthreads();
#pragma unroll
  for (int i = 0; i < 4; ++i)
    WT[(size_t)(bn + ty + i * 8) * DIN + bk + tx] = f32_bf16(tile[tx][ty + i * 8]);
}

// ---------------------------------------------------------------- phase 1
__device__ __forceinline__ int lds_idx(int row, int slot) {  // ushort units
  return row * 32 + ((slot ^ ((row >> 1) & 3)) << 3);
}

__global__ __launch_bounds__(256) void k_xproj(
    const float* __restrict__ X,             // [B*S][DIN] fp32
    const unsigned short* __restrict__ WT,   // W_xh^T bf16 [n][k]
    unsigned short* __restrict__ XP) {       // bf16 [s][b][h]
  __shared__ unsigned short As[128 * 32];
  __shared__ unsigned short Bs[128 * 32];
  const int tid = threadIdx.x;
  const int m0 = (int)(blockIdx.x >> 3) * 128;
  const int n0 = (int)(blockIdx.x & 7) * 128;
  const int w = tid >> 6, lane = tid & 63;
  const int wm = (w >> 1) * 64, wn = (w & 1) * 64;
  const int l15 = lane & 15, lhi = lane >> 4;
  const int srow = tid >> 1;
  const int s0 = (tid & 1) * 2;
  f32x4 acc[4][4] = {};

  for (int k0 = 0; k0 < DIN; k0 += 32) {
    const float4* ga = reinterpret_cast<const float4*>(
        X + (size_t)(m0 + srow) * DIN + k0 + s0 * 8);
    float4 f0 = ga[0], f1 = ga[1], f2 = ga[2], f3 = ga[3];
    us8 v0, v1;
    v0[0] = f32_bf16(f0.x); v0[1] = f32_bf16(f0.y); v0[2] = f32_bf16(f0.z); v0[3] = f32_bf16(f0.w);
    v0[4] = f32_bf16(f1.x); v0[5] = f32_bf16(f1.y); v0[6] = f32_bf16(f1.z); v0[7] = f32_bf16(f1.w);
    v1[0] = f32_bf16(f2.x); v1[1] = f32_bf16(f2.y); v1[2] = f32_bf16(f2.z); v1[3] = f32_bf16(f2.w);
    v1[4] = f32_bf16(f3.x); v1[5] = f32_bf16(f3.y); v1[6] = f32_bf16(f3.z); v1[7] = f32_bf16(f3.w);
    *(us8*)&As[lds_idx(srow, s0)]     = v0;
    *(us8*)&As[lds_idx(srow, s0 + 1)] = v1;
    const unsigned short* gb = WT + (size_t)(n0 + srow) * DIN + k0 + s0 * 8;
    *(us8*)&Bs[lds_idx(srow, s0)]     = *reinterpret_cast<const us8*>(gb);
    *(us8*)&Bs[lds_idx(srow, s0 + 1)] = *reinterpret_cast<const us8*>(gb + 8);
    __syncthreads();

    bf8 af[4], bfr[4];
#pragma unroll
    for (int i = 0; i < 4; ++i)
      af[i] = as_bf8(*(const us8*)&As[lds_idx(wm + i * 16 + l15, lhi)]);
#pragma unroll
    for (int r = 0; r < 4; ++r)
      bfr[r] = as_bf8(*(const us8*)&Bs[lds_idx(wn + r * 16 + l15, lhi)]);
#pragma unroll
    for (int i = 0; i < 4; ++i)
#pragma unroll
      for (int r = 0; r < 4; ++r)
        acc[i][r] = __builtin_amdgcn_mfma_f32_16x16x32_bf16(af[i], bfr[r], acc[i][r], 0, 0, 0);
    __syncthreads();
  }
#pragma unroll
  for (int i = 0; i < 4; ++i)
#pragma unroll
    for (int r = 0; r < 4; ++r)
#pragma unroll
      for (int j = 0; j < 4; ++j) {
        int gm = m0 + wm + i * 16 + lhi * 4 + j;
        int gn = n0 + wn + r * 16 + l15;
        int orow = ((gm & 511) << 6) | (gm >> 9);
        XP[(size_t)orow * DH + gn] = f32_bf16(acc[i][r][j]);
      }
}

// ---------------------------------------------------------------- phase 2
// 64 WGs x 256 thr. WG g: bg=g>>4 (rows bg*16..+16), ng=g&15; wave w owns
// cols ng*64+w*16..+16. W_hh^T slice resident in 128 VGPRs/wave.
// Arrival: wave w adds to ctr[(bg*4+w)*64] after draining its h stores;
// line (bg,w) == 16*(t+1) means all wave-w producers of bg finished step t.
// Poll waits on all 4 lines (s_sleep backoff).
__global__ __launch_bounds__(256) void k_rnn(
    const unsigned short* __restrict__ WT,  // W_hh^T bf16 [n][k]
    const unsigned short* __restrict__ XP,  // bf16 [s][b][h]
    const float* __restrict__ BH,           // b_h fp32
    float* __restrict__ OUT,                // fp32 [b][s][h]
    unsigned short* __restrict__ H,         // 2 x [NB][DH] bf16
    unsigned int* __restrict__ ctr) {       // 4 bg x 4 wave lines, 256B apart
  __shared__ us8 hs[2][2048];               // 2 x 32KB
  const int tid = threadIdx.x, g = blockIdx.x;
  const int w = tid >> 6, lane = tid & 63;
  const int bg = g >> 4, ng = g & 15;
  const int nbase = ng * 64 + w * 16;
  const int rowbase = bg * 16;
  const int l15 = lane & 15, lhi = lane >> 4;
  const int crow = lhi * 4;
  const int th = tid >> 7;                  // staging row parity
  const int c7 = tid & 127;                 // staging chunk-in-row
  const int rbase = l15 * 128;              // read: row base (16B slots)
  const int rx = l15 & 7;                   // read: XOR key

  // preload W_hh^T fragments: 32 x 16B per lane = 128 VGPRs
  bf8 bw[32];
  const unsigned short* wp = WT + (size_t)(nbase + l15) * DIN + lhi * 8;
#pragma unroll
  for (int kk = 0; kk < 32; ++kk)
    bw[kk] = as_bf8(*reinterpret_cast<const us8*>(wp + kk * 32));

  const float bh = BH[nbase + l15];
  unsigned int* arr = &ctr[(bg * 4 + w) * 64];   // this wave's arrival line
  unsigned int* p0 = &ctr[(bg * 4 + 0) * 64];
  unsigned int* p1 = &ctr[(bg * 4 + 1) * 64];
  unsigned int* p2 = &ctr[(bg * 4 + 2) * 64];
  unsigned int* p3 = &ctr[(bg * 4 + 3) * 64];

  // prefetch xp for t=0
  float xq[4];
#pragma unroll
  for (int j = 0; j < 4; ++j)
    xq[j] = bf16_f32(XP[(size_t)(rowbase + crow + j) * DH + nbase + l15]);

  float v[4] = {0.f, 0.f, 0.f, 0.f};

#pragma unroll 1
  for (int t = 0; t < NS; ++t) {
    const int pb = t & 1;
    f32x4 a0 = {}, a1 = {}, a2 = {}, a3 = {};
    if (t > 0) {
      // ---- stage h[pb] -> hs[pb] (16B sc-bypass loads, lane-linear) ----
      const us8* hg = reinterpret_cast<const us8*>(H) +
                      (size_t)pb * 8192 + rowbase * 128 + tid;
      us8 hv[8];
#pragma unroll
      for (int i = 0; i < 8; ++i) hv[i] = load_sc16(hg + 256 * i);
      asm volatile("s_waitcnt vmcnt(0)" ::: "memory");  // staged loads ONLY
      __builtin_amdgcn_sched_barrier(0);
#pragma unroll
      for (int i = 0; i < 8; ++i) {
        const int r = 2 * i + th;
        hs[pb][r * 128 + (c7 ^ (r & 7))] = hv[i];
      }
      __syncthreads();  // the ONLY barrier per step
      // ---- OUT stores for t-1: issued here, acks drain under MFMA+tanh ----
#pragma unroll
      for (int j = 0; j < 4; ++j)
        __builtin_nontemporal_store(
            v[j],
            &OUT[((size_t)(rowbase + crow + j) * NS + (t - 1)) * DH + nbase + l15]);
      // ---- A-fragment reads + 32 MFMA ----
#pragma unroll
      for (int kk = 0; kk < 32; kk += 4) {
        bf8 h0 = as_bf8(hs[pb][rbase + (((kk + 0) * 4 + lhi) ^ rx)]);
        bf8 h1 = as_bf8(hs[pb][rbase + (((kk + 1) * 4 + lhi) ^ rx)]);
        bf8 h2 = as_bf8(hs[pb][rbase + (((kk + 2) * 4 + lhi) ^ rx)]);
        bf8 h3 = as_bf8(hs[pb][rbase + (((kk + 3) * 4 + lhi) ^ rx)]);
        a0 = __builtin_amdgcn_mfma_f32_16x16x32_bf16(h0, bw[kk],     a0, 0, 0, 0);
        a1 = __builtin_amdgcn_mfma_f32_16x16x32_bf16(h1, bw[kk + 1], a1, 0, 0, 0);
        a2 = __builtin_amdgcn_mfma_f32_16x16x32_bf16(h2, bw[kk + 2], a2, 0, 0, 0);
        a3 = __builtin_amdgcn_mfma_f32_16x16x32_bf16(h3, bw[kk + 3], a3, 0, 0, 0);
      }
    }
    f32x4 s = (a0 + a1) + (a2 + a3);

#pragma unroll
    for (int j = 0; j < 4; ++j) {
      float x = xq[j] + s[j] + bh;
      float e = __expf(-2.f * fabsf(x));
      float r = __fdividef(1.f - e, 1.f + e);
      v[j] = copysignf(r, x);
    }

    if (t < NS - 1) {
      // h stores to coherent point
      unsigned short* hnext = H + (size_t)(pb ^ 1) * (NB * DH);
#pragma unroll
      for (int j = 0; j < 4; ++j)
        __hip_atomic_store(hnext + (size_t)(rowbase + crow + j) * DH + nbase + l15,
                           f32_bf16(v[j]), __ATOMIC_RELAXED, __HIP_MEMORY_SCOPE_AGENT);
      asm volatile("s_waitcnt vmcnt(0)" ::: "memory");  // drains h AND old OUT
      if (lane == 0)  // per-wave arrival on this wave's own line
        __hip_atomic_fetch_add(arr, 1u, __ATOMIC_RELAXED, __HIP_MEMORY_SCOPE_AGENT);
      // xp prefetch rides under the poll
#pragma unroll
      for (int j = 0; j < 4; ++j)
        xq[j] = bf16_f32(XP[(size_t)(((t + 1) << 6) + rowbase + crow + j) * DH +
                            nbase + l15]);
      const unsigned tgt = 16u * (unsigned)(t + 1);
      for (unsigned it = 0;; ++it) {
        unsigned u0 = __hip_atomic_load(p0, __ATOMIC_RELAXED, __HIP_MEMORY_SCOPE_AGENT);
        unsigned u1 = __hip_atomic_load(p1, __ATOMIC_RELAXED, __HIP_MEMORY_SCOPE_AGENT);
        unsigned u2 = __hip_atomic_load(p2, __ATOMIC_RELAXED, __HIP_MEMORY_SCOPE_AGENT);
        unsigned u3 = __hip_atomic_load(p3, __ATOMIC_RELAXED, __HIP_MEMORY_SCOPE_AGENT);
        if ((u0 >= tgt) & (u1 >= tgt) & (u2 >= tgt) & (u3 >= tgt)) break;
        if (it > SPIN_CAP) break;  // safety: fail fast rather than hang
        __builtin_amdgcn_s_sleep(1);
      }
      asm volatile("" ::: "memory");  // no staging-load hoist above the poll
    }
  }
  // final OUT stores for t = NS-1
#pragma unroll
  for (int j = 0; j < 4; ++j)
    __builtin_nontemporal_store(
        v[j], &OUT[((size_t)(rowbase + crow + j) * NS + (NS - 1)) * DH + nbase + l15]);
}

// ---------------------------------------------------------------- launcher
extern "C" void kernel_launch(void* const* d_in, const int* in_sizes, int n_in,
                              void* d_out, int out_size, void* d_ws, size_t ws_size,
                              hipStream_t stream) {
  (void)in_sizes; (void)n_in; (void)out_size; (void)ws_size;
  const float* X   = (const float*)d_in[0];
  const float* Wxh = (const float*)d_in[1];
  const float* Whh = (const float*)d_in[2];
  const float* bh  = (const float*)d_in[3];
  float* out = (float*)d_out;

  char* ws = (char*)d_ws;
  // layout: wxh_t 2MB | whh_t 2MB | xp 64MB | h 256KB | ctr 4KB
  unsigned short* wxh_t = (unsigned short*)(ws);
  unsigned short* whh_t = (unsigned short*)(ws + (size_t)2 * 1024 * 1024);
  unsigned short* xp    = (unsigned short*)(ws + (size_t)4 * 1024 * 1024);
  unsigned short* hbuf  = (unsigned short*)(ws + 71303168ull);
  unsigned int*   ctr   = (unsigned int*)(ws + 71565312ull);

  (void)hipMemsetAsync(ctr, 0, 4096, stream);  // counters start at 0 each call
  k_transpose_bf16<<<1024, 256, 0, stream>>>(Wxh, wxh_t);
  k_transpose_bf16<<<1024, 256, 0, stream>>>(Whh, whh_t);
  k_xproj<<<2048, 256, 0, stream>>>(X, wxh_t, xp);
  k_rnn<<<64, 256, 0, stream>>>(whh_t, xp, bh, out, hbuf, ctr);
}